// Round 7
// baseline (966.492 us; speedup 1.0000x reference)
//
#include <hip/hip_runtime.h>
#include <math.h>
#include <stdint.h>

#define N_TOK 4096
#define DIM   1024
#define HID   2048
#define NE    8
#define NROWS (N_TOK * 2)   // 8192 (token, k) assignments

typedef __attribute__((ext_vector_type(8))) short bf16x8;
typedef __attribute__((ext_vector_type(4))) float f32x4;

__device__ __forceinline__ unsigned short f2bf(float f) {
    union { unsigned int i; float f; } v; v.f = f;
    unsigned int u = v.i;
    return (unsigned short)((u + 0x7FFFu + ((u >> 16) & 1u)) >> 16);
}
__device__ __forceinline__ int clampi(int v, int lo, int hi) {
    return v < lo ? lo : (v > hi ? hi : v);
}
// 8 consecutive fp32 -> 8 bf16
__device__ __forceinline__ void load8f(const float* p, unsigned short* o) {
    float4 a = *(const float4*)p;
    float4 b = *(const float4*)(p + 4);
    o[0] = f2bf(a.x); o[1] = f2bf(a.y); o[2] = f2bf(a.z); o[3] = f2bf(a.w);
    o[4] = f2bf(b.x); o[5] = f2bf(b.y); o[6] = f2bf(b.z); o[7] = f2bf(b.w);
}

// ---------------- init: zero counts/cursors + ybuf accumulator ----------------
__global__ __launch_bounds__(256) void init_kernel(int* __restrict__ hdr, float4* __restrict__ ybuf4) {
    int i = blockIdx.x * 256 + threadIdx.x;     // 4096 blocks -> 1M float4 = 4M floats
    ybuf4[i] = make_float4(0.f, 0.f, 0.f, 0.f);
    if (i < 32) hdr[i] = 0;
}

// ---------------- gating: one wave per token, pure fp32 ----------------
__global__ __launch_bounds__(256) void gate_kernel(
    const float* __restrict__ x, const float* __restrict__ wg,
    int* __restrict__ counts, int* __restrict__ top_e, float* __restrict__ top_g)
{
    int wave = threadIdx.x >> 6;
    int lane = threadIdx.x & 63;
    int n = blockIdx.x * 4 + wave;
    if (n >= N_TOK) return;
    float acc[NE];
#pragma unroll
    for (int e = 0; e < NE; e++) acc[e] = 0.f;
    const float* xrow = x + (size_t)n * DIM;
    for (int d = lane; d < DIM; d += 64) {
        float xv = xrow[d];
        float4 wa = *(const float4*)(wg + (size_t)d * NE);
        float4 wb = *(const float4*)(wg + (size_t)d * NE + 4);
        acc[0] += xv * wa.x; acc[1] += xv * wa.y;
        acc[2] += xv * wa.z; acc[3] += xv * wa.w;
        acc[4] += xv * wb.x; acc[5] += xv * wb.y;
        acc[6] += xv * wb.z; acc[7] += xv * wb.w;
    }
#pragma unroll
    for (int e = 0; e < NE; e++) {
        float v = acc[e];
#pragma unroll
        for (int off = 32; off > 0; off >>= 1) v += __shfl_xor(v, off, 64);
        acc[e] = v;
    }
    if (lane == 0) {
        int e0 = 0; float v0 = acc[0];
#pragma unroll
        for (int e = 1; e < NE; e++) if (acc[e] > v0) { v0 = acc[e]; e0 = e; }
        int e1 = (e0 == 0) ? 1 : 0; float v1 = acc[e1];
#pragma unroll
        for (int e = 0; e < NE; e++) if (e != e0 && acc[e] > v1) { v1 = acc[e]; e1 = e; }
        float s = expf(v1 - v0);      // softmax over [v0, v1]; s <= 1
        float g0 = 1.f / (1.f + s);
        float g1 = s / (1.f + s);
        atomicAdd(&counts[e0], 1);
        atomicAdd(&counts[e1], 1);
        top_e[n] = e0 | (e1 << 8);
        top_g[2 * n + 0] = g0;
        top_g[2 * n + 1] = g1;
    }
}

// ---------------- scatter: build per-expert row lists ----------------
__global__ __launch_bounds__(256) void scatter_kernel(
    const int* __restrict__ counts, int* __restrict__ cursors,
    const int* __restrict__ top_e, const float* __restrict__ top_g,
    int* __restrict__ row_tok, float* __restrict__ row_gate)
{
    int n = blockIdx.x * 256 + threadIdx.x;
    if (n >= N_TOK) return;
    int off[NE]; int a = 0;
#pragma unroll
    for (int e = 0; e < NE; e++) { off[e] = a; a += clampi(counts[e], 0, NROWS); }
    int te = top_e[n];
#pragma unroll
    for (int k = 0; k < 2; k++) {
        int e = clampi((k == 0) ? (te & 0xFF) : ((te >> 8) & 0xFF), 0, NE - 1);
        int pos = atomicAdd(&cursors[e], 1);
        int r = clampi(off[e] + pos, 0, NROWS - 1);
        row_tok[r]  = n;
        row_gate[r] = top_g[2 * n + k];
    }
}

// ---------------- FFN1 (sparse): h = gelu(x_rows @ w1[e] + b1[e]) ----------------
__global__ __launch_bounds__(256) void ffn1_kernel(
    const float* __restrict__ x,
    const float* __restrict__ w1,
    const float* __restrict__ b1,
    const int* __restrict__ counts,
    const int* __restrict__ row_tok,
    unsigned short* __restrict__ h)
{
    int e  = blockIdx.x >> 6;
    int mb = blockIdx.x & 63;
    int nb = blockIdx.y;
    int off = 0;
#pragma unroll
    for (int i = 0; i < NE; i++) { int c = clampi(counts[i], 0, NROWS); if (i < e) off += c; }
    int cnt  = clampi(counts[e], 0, NROWS);
    int row0 = mb * 64;
    if (row0 >= cnt) return;
    int nvalid = clampi(cnt - row0, 1, 64);

    __shared__ __align__(16) unsigned short lA[64 * 40];
    __shared__ __align__(16) unsigned short lB[64 * 40];
    __shared__ int ltok[64];

    int t = threadIdx.x;
    if (t < 64) {
        int rl = clampi(t, 0, nvalid - 1);
        int idx = clampi(off + row0 + rl, 0, NROWS - 1);
        ltok[t] = clampi(row_tok[idx], 0, N_TOK - 1);
    }
    __syncthreads();

    int wv = t >> 6, lane = t & 63, quad = lane >> 4, ln = lane & 15;
    f32x4 acc[4];
#pragma unroll
    for (int s = 0; s < 4; s++) acc[s] = (f32x4){0.f, 0.f, 0.f, 0.f};

    int ai = t >> 2, ac = t & 3;   // A staging: 64 rows x 4 chunks of 8
    int bk = t >> 3, bc = t & 7;   // B staging: 32 k-rows x 8 chunks of 8
    const int n0 = nb * 64;
    const float* Arow  = x + (size_t)ltok[ai] * DIM + ac * 8;
    const float* Bbase = w1 + (size_t)e * DIM * HID + n0;

    for (int kt = 0; kt < DIM / 32; kt++) {
        int k0 = kt * 32;
        unsigned short a8[8], b8[8];
        load8f(Arow + k0, a8);
        load8f(Bbase + (size_t)(k0 + bk) * HID + bc * 8, b8);
        *(uint4*)(&lA[ai * 40 + ac * 8]) = *(uint4*)a8;
#pragma unroll
        for (int j = 0; j < 8; j++) lB[(bc * 8 + j) * 40 + bk] = b8[j];
        __syncthreads();
        bf16x8 afr = *(const bf16x8*)(&lA[(wv * 16 + ln) * 40 + quad * 8]);
#pragma unroll
        for (int s = 0; s < 4; s++) {
            bf16x8 bfr = *(const bf16x8*)(&lB[(s * 16 + ln) * 40 + quad * 8]);
            acc[s] = __builtin_amdgcn_mfma_f32_16x16x32_bf16(afr, bfr, acc[s], 0, 0, 0);
        }
        __syncthreads();
    }

    int gr0 = off + row0;
#pragma unroll
    for (int s = 0; s < 4; s++) {
        int col = n0 + s * 16 + ln;
        float bias = b1[e * HID + col];
#pragma unroll
        for (int r = 0; r < 4; r++) {
            int ml = wv * 16 + quad * 4 + r;
            if (ml < nvalid) {
                float vv = acc[s][r] + bias;
                float c = 0.7978845608028654f * (vv + 0.044715f * vv * vv * vv);
                float g = 0.5f * vv * (1.f + tanhf(c));
                int hr = clampi(gr0 + ml, 0, NROWS - 1);
                h[(size_t)hr * HID + col] = f2bf(g);
            }
        }
    }
}

// ---------------- FFN2 (sparse): ybuf[tok] += (h_rows @ w2[e] + b2[e]) * gate ----------------
__global__ __launch_bounds__(256) void ffn2_kernel(
    const unsigned short* __restrict__ h,
    const float* __restrict__ w2,
    const float* __restrict__ b2,
    const int* __restrict__ counts,
    const int* __restrict__ row_tok,
    const float* __restrict__ row_gate,
    float* __restrict__ ybuf)
{
    int e  = blockIdx.x >> 6;
    int mb = blockIdx.x & 63;
    int nb = blockIdx.y;
    int off = 0;
#pragma unroll
    for (int i = 0; i < NE; i++) { int c = clampi(counts[i], 0, NROWS); if (i < e) off += c; }
    int cnt  = clampi(counts[e], 0, NROWS);
    int row0 = mb * 64;
    if (row0 >= cnt) return;
    int nvalid = clampi(cnt - row0, 1, 64);

    __shared__ __align__(16) unsigned short lA[64 * 40];
    __shared__ __align__(16) unsigned short lB[64 * 40];
    __shared__ int   ltok2[64];
    __shared__ float lgate[64];

    int t = threadIdx.x;
    if (t < 64) {
        int rl = clampi(t, 0, nvalid - 1);
        int idx = clampi(off + row0 + rl, 0, NROWS - 1);
        ltok2[t] = clampi(row_tok[idx], 0, N_TOK - 1);
        lgate[t] = row_gate[idx];
    }
    __syncthreads();

    int wv = t >> 6, lane = t & 63, quad = lane >> 4, ln = lane & 15;
    f32x4 acc[4];
#pragma unroll
    for (int s = 0; s < 4; s++) acc[s] = (f32x4){0.f, 0.f, 0.f, 0.f};

    int ai = t >> 2, ac = t & 3;
    int bk = t >> 3, bc = t & 7;
    const int n0 = nb * 64;
    int arow_idx = clampi(off + row0 + clampi(ai, 0, nvalid - 1), 0, NROWS - 1);
    const unsigned short* Arow = h + (size_t)arow_idx * HID + ac * 8;
    const float* Bbase = w2 + (size_t)e * HID * DIM + n0;

    for (int kt = 0; kt < HID / 32; kt++) {
        int k0 = kt * 32;
        uint4 av = *(const uint4*)(Arow + k0);          // h is bf16
        unsigned short b8[8];
        load8f(Bbase + (size_t)(k0 + bk) * DIM + bc * 8, b8);
        *(uint4*)(&lA[ai * 40 + ac * 8]) = av;
#pragma unroll
        for (int j = 0; j < 8; j++) lB[(bc * 8 + j) * 40 + bk] = b8[j];
        __syncthreads();
        bf16x8 afr = *(const bf16x8*)(&lA[(wv * 16 + ln) * 40 + quad * 8]);
#pragma unroll
        for (int s = 0; s < 4; s++) {
            bf16x8 bfr = *(const bf16x8*)(&lB[(s * 16 + ln) * 40 + quad * 8]);
            acc[s] = __builtin_amdgcn_mfma_f32_16x16x32_bf16(afr, bfr, acc[s], 0, 0, 0);
        }
        __syncthreads();
    }

#pragma unroll
    for (int s = 0; s < 4; s++) {
        int col = n0 + s * 16 + ln;
        float bias = b2[e * DIM + col];
#pragma unroll
        for (int r = 0; r < 4; r++) {
            int ml = wv * 16 + quad * 4 + r;
            if (ml < nvalid) {
                float vv = (acc[s][r] + bias) * lgate[ml];
                atomicAdd(&ybuf[(size_t)ltok2[ml] * DIM + col], vv);
            }
        }
    }
}

// ---------------- copy: out(fp32) = ybuf ----------------
__global__ __launch_bounds__(256) void copy_kernel(
    const float4* __restrict__ ybuf4, float4* __restrict__ out4)
{
    int i = blockIdx.x * 256 + threadIdx.x;   // 1M float4
    out4[i] = ybuf4[i];
}

__global__ __launch_bounds__(256) void zero_out_kernel(float* __restrict__ out) {
    int i = blockIdx.x * 256 + threadIdx.x;
    out[i] = 0.f;
}

extern "C" void kernel_launch(void* const* d_in, const int* in_sizes, int n_in,
                              void* d_out, int out_size, void* d_ws, size_t ws_size,
                              hipStream_t stream) {
    const float* x  = (const float*)d_in[0];
    const float* wg = (const float*)d_in[1];
    const float* w1 = (const float*)d_in[2];
    const float* b1 = (const float*)d_in[3];
    const float* w2 = (const float*)d_in[4];
    const float* b2 = (const float*)d_in[5];
    float* out = (float*)d_out;               // reference output dtype = float32

    // Workspace layout (~48.13 MiB):
    //   [0, 128)           counts(8 int) + cursors(8 int)  (zeroed by init_kernel)
    //   [256, 16640)       top_e  int[4096]
    //   [16640, 49408)     top_g  float[8192]
    //   [49408, 82176)     row_tok int[8192]
    //   [82176, 114944)    row_gate float[8192]
    //   [128K, 128K+32M)   hbuf  bf16[8192][2048]
    //   [128K+32M, +16M)   ybuf  f32[4096][1024]
    const size_t HBUF_OFF = (size_t)1 << 17;
    const size_t YBUF_OFF = HBUF_OFF + (size_t)NROWS * HID * 2;
    const size_t NEEDED   = YBUF_OFF + (size_t)N_TOK * DIM * 4;

    if (ws_size < NEEDED) {
        zero_out_kernel<<<dim3(N_TOK * DIM / 256), dim3(256), 0, stream>>>(out);
        return;
    }

    char* ws = (char*)d_ws;
    int*   counts   = (int*)(ws + 0);
    int*   cursors  = (int*)(ws + 64);
    int*   top_e    = (int*)(ws + 256);
    float* top_g    = (float*)(ws + 16640);
    int*   row_tok  = (int*)(ws + 49408);
    float* row_gate = (float*)(ws + 82176);
    unsigned short* hbuf = (unsigned short*)(ws + HBUF_OFF);
    float* ybuf = (float*)(ws + YBUF_OFF);

    init_kernel<<<dim3(N_TOK * DIM / 1024), dim3(256), 0, stream>>>((int*)ws, (float4*)ybuf);
    gate_kernel<<<dim3(N_TOK / 4), dim3(256), 0, stream>>>(x, wg, counts, top_e, top_g);
    scatter_kernel<<<dim3(N_TOK / 256), dim3(256), 0, stream>>>(counts, cursors, top_e, top_g, row_tok, row_gate);
    ffn1_kernel<<<dim3(NE * 64, HID / 64), dim3(256), 0, stream>>>(x, w1, b1, counts, row_tok, hbuf);
    ffn2_kernel<<<dim3(NE * 64, DIM / 64), dim3(256), 0, stream>>>(hbuf, w2, b2, counts, row_tok, row_gate, ybuf);
    copy_kernel<<<dim3(N_TOK * DIM / 1024), dim3(256), 0, stream>>>((const float4*)ybuf, (float4*)out);
}

// Round 8
// 907.259 us; speedup vs baseline: 1.0653x; 1.0653x over previous
//
#include <hip/hip_runtime.h>
#include <math.h>
#include <stdint.h>

#define N_TOK 4096
#define DIM   1024
#define HID   2048
#define NE    8
#define NROWS (N_TOK * 2)   // 8192 (token, k) assignments
#define LDST  72            // LDS tile stride in shorts (36 dwords; balanced banks, 16B-aligned)

typedef __attribute__((ext_vector_type(8))) short bf16x8;
typedef __attribute__((ext_vector_type(4))) float f32x4;

__device__ __forceinline__ unsigned short f2bf(float f) {
    union { unsigned int i; float f; } v; v.f = f;
    unsigned int u = v.i;
    return (unsigned short)((u + 0x7FFFu + ((u >> 16) & 1u)) >> 16);
}
__device__ __forceinline__ int clampi(int v, int lo, int hi) {
    return v < lo ? lo : (v > hi ? hi : v);
}
__device__ __forceinline__ void cvt8(const float* p, unsigned short* o) {
    float4 a = *(const float4*)p;
    float4 b = *(const float4*)(p + 4);
    o[0] = f2bf(a.x); o[1] = f2bf(a.y); o[2] = f2bf(a.z); o[3] = f2bf(a.w);
    o[4] = f2bf(b.x); o[5] = f2bf(b.y); o[6] = f2bf(b.z); o[7] = f2bf(b.w);
}

// ---------------- init (fast path): zero header + d_out ----------------
__global__ __launch_bounds__(256) void init_out_kernel(int* __restrict__ hdr, float4* __restrict__ out4) {
    int i = blockIdx.x * 256 + threadIdx.x;     // 4096 blocks -> 1M float4
    out4[i] = make_float4(0.f, 0.f, 0.f, 0.f);
    if (i < 32) hdr[i] = 0;
}

// ---------------- gating: one wave per token, pure fp32 ----------------
__global__ __launch_bounds__(256) void gate_kernel(
    const float* __restrict__ x, const float* __restrict__ wg,
    int* __restrict__ counts, int* __restrict__ top_e, float* __restrict__ top_g)
{
    int wave = threadIdx.x >> 6;
    int lane = threadIdx.x & 63;
    int n = blockIdx.x * 4 + wave;
    if (n >= N_TOK) return;
    float acc[NE];
#pragma unroll
    for (int e = 0; e < NE; e++) acc[e] = 0.f;
    const float* xrow = x + (size_t)n * DIM;
    for (int d = lane; d < DIM; d += 64) {
        float xv = xrow[d];
        float4 wa = *(const float4*)(wg + (size_t)d * NE);
        float4 wb = *(const float4*)(wg + (size_t)d * NE + 4);
        acc[0] += xv * wa.x; acc[1] += xv * wa.y;
        acc[2] += xv * wa.z; acc[3] += xv * wa.w;
        acc[4] += xv * wb.x; acc[5] += xv * wb.y;
        acc[6] += xv * wb.z; acc[7] += xv * wb.w;
    }
#pragma unroll
    for (int e = 0; e < NE; e++) {
        float v = acc[e];
#pragma unroll
        for (int off = 32; off > 0; off >>= 1) v += __shfl_xor(v, off, 64);
        acc[e] = v;
    }
    if (lane == 0) {
        int e0 = 0; float v0 = acc[0];
#pragma unroll
        for (int e = 1; e < NE; e++) if (acc[e] > v0) { v0 = acc[e]; e0 = e; }
        int e1 = (e0 == 0) ? 1 : 0; float v1 = acc[e1];
#pragma unroll
        for (int e = 0; e < NE; e++) if (e != e0 && acc[e] > v1) { v1 = acc[e]; e1 = e; }
        float s = expf(v1 - v0);
        float g0 = 1.f / (1.f + s);
        float g1 = s / (1.f + s);
        atomicAdd(&counts[e0], 1);
        atomicAdd(&counts[e1], 1);
        top_e[n] = e0 | (e1 << 8);
        top_g[2 * n + 0] = g0;
        top_g[2 * n + 1] = g1;
    }
}

// ---------------- scatter: build per-expert row lists ----------------
__global__ __launch_bounds__(256) void scatter_kernel(
    const int* __restrict__ counts, int* __restrict__ cursors,
    const int* __restrict__ top_e, const float* __restrict__ top_g,
    int* __restrict__ row_tok, float* __restrict__ row_gate)
{
    int n = blockIdx.x * 256 + threadIdx.x;
    if (n >= N_TOK) return;
    int off[NE]; int a = 0;
#pragma unroll
    for (int e = 0; e < NE; e++) { off[e] = a; a += clampi(counts[e], 0, NROWS); }
    int te = top_e[n];
#pragma unroll
    for (int k = 0; k < 2; k++) {
        int e = clampi((k == 0) ? (te & 0xFF) : ((te >> 8) & 0xFF), 0, NE - 1);
        int pos = atomicAdd(&cursors[e], 1);
        int r = clampi(off[e] + pos, 0, NROWS - 1);
        row_tok[r]  = n;
        row_gate[r] = top_g[2 * n + k];
    }
}

// ---------------- transpose+cast: in[e][K][N] fp32 -> out[e][N][K] bf16 ----------------
__global__ __launch_bounds__(256) void transpose_kernel(
    const float* __restrict__ in, unsigned short* __restrict__ outp, int K, int N)
{
    int e  = blockIdx.z;
    int kb = blockIdx.x;        // K/64 tiles
    int nb = blockIdx.y;        // N/64 tiles
    __shared__ __align__(16) unsigned short tile[64 * LDST];
    int t = threadIdx.x;

    // load: r = t>>2 (0..63), cq = t&3 -> 16 cols
    int r = t >> 2, cq = t & 3;
    const float* sp = in + ((size_t)e * K + kb * 64 + r) * N + nb * 64 + cq * 16;
    unsigned short v[16];
    cvt8(sp, v);
    cvt8(sp + 8, v + 8);
    *(uint4*)(&tile[r * LDST + cq * 16 + 0]) = *(uint4*)(v + 0);
    *(uint4*)(&tile[r * LDST + cq * 16 + 8]) = *(uint4*)(v + 8);
    __syncthreads();

    // store transposed: c = t>>2 (out row), kq = t&3 -> 16 k
    int c = t >> 2, kq = t & 3;
    unsigned short o[16];
#pragma unroll
    for (int i = 0; i < 16; i++) o[i] = tile[(kq * 16 + i) * LDST + c];
    unsigned short* dp = outp + ((size_t)e * N + nb * 64 + c) * K + kb * 64 + kq * 16;
    *(uint4*)(dp + 0) = *(uint4*)(o + 0);
    *(uint4*)(dp + 8) = *(uint4*)(o + 8);
}

// ---------------- FFN1 fast: 128x128 tile, BK=64, w1T bf16 ----------------
__global__ __launch_bounds__(256) void ffn1_fast(
    const float* __restrict__ x,
    const unsigned short* __restrict__ w1t,   // [e][H][D] bf16
    const float* __restrict__ b1,
    const int* __restrict__ counts,
    const int* __restrict__ row_tok,
    unsigned short* __restrict__ h)
{
    int e  = blockIdx.x >> 6;
    int mb = blockIdx.x & 63;
    int nb = blockIdx.y;
    int off = 0;
#pragma unroll
    for (int i = 0; i < NE; i++) { int c = clampi(counts[i], 0, NROWS); if (i < e) off += c; }
    int cnt  = clampi(counts[e], 0, NROWS);
    int row0 = mb * 128;
    if (row0 >= cnt) return;
    int nvalid = clampi(cnt - row0, 1, 128);

    __shared__ __align__(16) unsigned short lA[128 * LDST];  // 18 KB
    __shared__ __align__(16) unsigned short lB[128 * LDST];  // 18 KB
    __shared__ int ltok[128];

    int t = threadIdx.x;
    if (t < 128) {
        int rl = clampi(t, 0, nvalid - 1);
        int idx = clampi(off + row0 + rl, 0, NROWS - 1);
        ltok[t] = clampi(row_tok[idx], 0, N_TOK - 1);
    }
    __syncthreads();

    const int n0 = nb * 128;
    // staging assignment: 1024 16B-chunks (128 rows x 8 kc), 4 per thread
    const float* aptr[4];
    const unsigned short* bptr[4];
    int lofs[4];
#pragma unroll
    for (int i = 0; i < 4; i++) {
        int id = i * 256 + t;
        int row = id >> 3, kc = id & 7;
        aptr[i] = x + (size_t)ltok[row] * DIM + kc * 8;
        bptr[i] = w1t + ((size_t)e * HID + n0 + row) * DIM + kc * 8;
        lofs[i] = row * LDST + kc * 8;
    }

    int wv = t >> 6, lane = t & 63, quad = lane >> 4, ln = lane & 15;
    int wr = wv >> 1, wc = wv & 1;
    f32x4 acc[4][4];
#pragma unroll
    for (int i = 0; i < 4; i++)
#pragma unroll
        for (int j = 0; j < 4; j++) acc[i][j] = (f32x4){0.f, 0.f, 0.f, 0.f};

    for (int kt = 0; kt < DIM / 64; kt++) {
        int k0 = kt * 64;
#pragma unroll
        for (int i = 0; i < 4; i++) {
            unsigned short a8[8];
            cvt8(aptr[i] + k0, a8);
            *(uint4*)(&lA[lofs[i]]) = *(uint4*)a8;
            *(uint4*)(&lB[lofs[i]]) = *(const uint4*)(bptr[i] + k0);
        }
        __syncthreads();
#pragma unroll
        for (int kk = 0; kk < 2; kk++) {
            bf16x8 af[4], bf[4];
#pragma unroll
            for (int s = 0; s < 4; s++)
                af[s] = *(const bf16x8*)(&lA[(wr * 64 + s * 16 + ln) * LDST + kk * 32 + quad * 8]);
#pragma unroll
            for (int s = 0; s < 4; s++)
                bf[s] = *(const bf16x8*)(&lB[(wc * 64 + s * 16 + ln) * LDST + kk * 32 + quad * 8]);
#pragma unroll
            for (int i = 0; i < 4; i++)
#pragma unroll
                for (int j = 0; j < 4; j++)
                    acc[i][j] = __builtin_amdgcn_mfma_f32_16x16x32_bf16(af[i], bf[j], acc[i][j], 0, 0, 0);
        }
        __syncthreads();
    }

    int gr0 = off + row0;
#pragma unroll
    for (int j = 0; j < 4; j++) {
        int col = n0 + wc * 64 + j * 16 + ln;
        float bias = b1[e * HID + col];
#pragma unroll
        for (int i = 0; i < 4; i++) {
#pragma unroll
            for (int r = 0; r < 4; r++) {
                int m = wr * 64 + i * 16 + quad * 4 + r;
                if (m < nvalid) {
                    float vv = acc[i][j][r] + bias;
                    float c = 0.7978845608028654f * (vv + 0.044715f * vv * vv * vv);
                    float g = 0.5f * vv * (1.f + tanhf(c));
                    h[(size_t)(gr0 + m) * HID + col] = f2bf(g);
                }
            }
        }
    }
}

// ---------------- FFN2 fast: 128x128 tile, BK=64, w2T bf16, atomic into out ----------------
__global__ __launch_bounds__(256) void ffn2_fast(
    const unsigned short* __restrict__ h,
    const unsigned short* __restrict__ w2t,   // [e][D][H] bf16
    const float* __restrict__ b2,
    const int* __restrict__ counts,
    const int* __restrict__ row_tok,
    const float* __restrict__ row_gate,
    float* __restrict__ out)
{
    int e  = blockIdx.x >> 6;
    int mb = blockIdx.x & 63;
    int nb = blockIdx.y;
    int off = 0;
#pragma unroll
    for (int i = 0; i < NE; i++) { int c = clampi(counts[i], 0, NROWS); if (i < e) off += c; }
    int cnt  = clampi(counts[e], 0, NROWS);
    int row0 = mb * 128;
    if (row0 >= cnt) return;
    int nvalid = clampi(cnt - row0, 1, 128);

    __shared__ __align__(16) unsigned short lA[128 * LDST];
    __shared__ __align__(16) unsigned short lB[128 * LDST];
    __shared__ int   ltok2[128];
    __shared__ float lgate[128];

    int t = threadIdx.x;
    if (t < 128) {
        int rl = clampi(t, 0, nvalid - 1);
        int idx = clampi(off + row0 + rl, 0, NROWS - 1);
        ltok2[t] = clampi(row_tok[idx], 0, N_TOK - 1);
        lgate[t] = row_gate[idx];
    }
    __syncthreads();

    const int n0 = nb * 128;
    const unsigned short* aptr[4];
    const unsigned short* bptr[4];
    int lofs[4];
#pragma unroll
    for (int i = 0; i < 4; i++) {
        int id = i * 256 + t;
        int row = id >> 3, kc = id & 7;
        int arow = clampi(off + row0 + clampi(row, 0, nvalid - 1), 0, NROWS - 1);
        aptr[i] = h + (size_t)arow * HID + kc * 8;
        bptr[i] = w2t + ((size_t)e * DIM + n0 + row) * HID + kc * 8;
        lofs[i] = row * LDST + kc * 8;
    }

    int wv = t >> 6, lane = t & 63, quad = lane >> 4, ln = lane & 15;
    int wr = wv >> 1, wc = wv & 1;
    f32x4 acc[4][4];
#pragma unroll
    for (int i = 0; i < 4; i++)
#pragma unroll
        for (int j = 0; j < 4; j++) acc[i][j] = (f32x4){0.f, 0.f, 0.f, 0.f};

    for (int kt = 0; kt < HID / 64; kt++) {
        int k0 = kt * 64;
#pragma unroll
        for (int i = 0; i < 4; i++) {
            *(uint4*)(&lA[lofs[i]]) = *(const uint4*)(aptr[i] + k0);
            *(uint4*)(&lB[lofs[i]]) = *(const uint4*)(bptr[i] + k0);
        }
        __syncthreads();
#pragma unroll
        for (int kk = 0; kk < 2; kk++) {
            bf16x8 af[4], bf[4];
#pragma unroll
            for (int s = 0; s < 4; s++)
                af[s] = *(const bf16x8*)(&lA[(wr * 64 + s * 16 + ln) * LDST + kk * 32 + quad * 8]);
#pragma unroll
            for (int s = 0; s < 4; s++)
                bf[s] = *(const bf16x8*)(&lB[(wc * 64 + s * 16 + ln) * LDST + kk * 32 + quad * 8]);
#pragma unroll
            for (int i = 0; i < 4; i++)
#pragma unroll
                for (int j = 0; j < 4; j++)
                    acc[i][j] = __builtin_amdgcn_mfma_f32_16x16x32_bf16(af[i], bf[j], acc[i][j], 0, 0, 0);
        }
        __syncthreads();
    }

#pragma unroll
    for (int j = 0; j < 4; j++) {
        int col = n0 + wc * 64 + j * 16 + ln;
        float bias = b2[e * DIM + col];
#pragma unroll
        for (int i = 0; i < 4; i++) {
#pragma unroll
            for (int r = 0; r < 4; r++) {
                int m = wr * 64 + i * 16 + quad * 4 + r;
                if (m < nvalid) {
                    float vv = (acc[i][j][r] + bias) * lgate[m];
                    atomicAdd(&out[(size_t)ltok2[m] * DIM + col], vv);
                }
            }
        }
    }
}

// ================= slow fallback path (round-7, known-good) =================
__device__ __forceinline__ void load8f(const float* p, unsigned short* o) { cvt8(p, o); }

__global__ __launch_bounds__(256) void init_kernel(int* __restrict__ hdr, float4* __restrict__ ybuf4) {
    int i = blockIdx.x * 256 + threadIdx.x;
    ybuf4[i] = make_float4(0.f, 0.f, 0.f, 0.f);
    if (i < 32) hdr[i] = 0;
}

__global__ __launch_bounds__(256) void ffn1_kernel(
    const float* __restrict__ x, const float* __restrict__ w1, const float* __restrict__ b1,
    const int* __restrict__ counts, const int* __restrict__ row_tok, unsigned short* __restrict__ h)
{
    int e  = blockIdx.x >> 6;
    int mb = blockIdx.x & 63;
    int nb = blockIdx.y;
    int off = 0;
#pragma unroll
    for (int i = 0; i < NE; i++) { int c = clampi(counts[i], 0, NROWS); if (i < e) off += c; }
    int cnt  = clampi(counts[e], 0, NROWS);
    int row0 = mb * 64;
    if (row0 >= cnt) return;
    int nvalid = clampi(cnt - row0, 1, 64);

    __shared__ __align__(16) unsigned short lA[64 * 40];
    __shared__ __align__(16) unsigned short lB[64 * 40];
    __shared__ int ltok[64];

    int t = threadIdx.x;
    if (t < 64) {
        int rl = clampi(t, 0, nvalid - 1);
        int idx = clampi(off + row0 + rl, 0, NROWS - 1);
        ltok[t] = clampi(row_tok[idx], 0, N_TOK - 1);
    }
    __syncthreads();

    int wv = t >> 6, lane = t & 63, quad = lane >> 4, ln = lane & 15;
    f32x4 acc[4];
#pragma unroll
    for (int s = 0; s < 4; s++) acc[s] = (f32x4){0.f, 0.f, 0.f, 0.f};

    int ai = t >> 2, ac = t & 3;
    int bk = t >> 3, bc = t & 7;
    const int n0 = nb * 64;
    const float* Arow  = x + (size_t)ltok[ai] * DIM + ac * 8;
    const float* Bbase = w1 + (size_t)e * DIM * HID + n0;

    for (int kt = 0; kt < DIM / 32; kt++) {
        int k0 = kt * 32;
        unsigned short a8[8], b8[8];
        load8f(Arow + k0, a8);
        load8f(Bbase + (size_t)(k0 + bk) * HID + bc * 8, b8);
        *(uint4*)(&lA[ai * 40 + ac * 8]) = *(uint4*)a8;
#pragma unroll
        for (int j = 0; j < 8; j++) lB[(bc * 8 + j) * 40 + bk] = b8[j];
        __syncthreads();
        bf16x8 afr = *(const bf16x8*)(&lA[(wv * 16 + ln) * 40 + quad * 8]);
#pragma unroll
        for (int s = 0; s < 4; s++) {
            bf16x8 bfr = *(const bf16x8*)(&lB[(s * 16 + ln) * 40 + quad * 8]);
            acc[s] = __builtin_amdgcn_mfma_f32_16x16x32_bf16(afr, bfr, acc[s], 0, 0, 0);
        }
        __syncthreads();
    }

    int gr0 = off + row0;
#pragma unroll
    for (int s = 0; s < 4; s++) {
        int col = n0 + s * 16 + ln;
        float bias = b1[e * HID + col];
#pragma unroll
        for (int r = 0; r < 4; r++) {
            int ml = wv * 16 + quad * 4 + r;
            if (ml < nvalid) {
                float vv = acc[s][r] + bias;
                float c = 0.7978845608028654f * (vv + 0.044715f * vv * vv * vv);
                float g = 0.5f * vv * (1.f + tanhf(c));
                int hr = clampi(gr0 + ml, 0, NROWS - 1);
                h[(size_t)hr * HID + col] = f2bf(g);
            }
        }
    }
}

__global__ __launch_bounds__(256) void ffn2_kernel(
    const unsigned short* __restrict__ h, const float* __restrict__ w2, const float* __restrict__ b2,
    const int* __restrict__ counts, const int* __restrict__ row_tok, const float* __restrict__ row_gate,
    float* __restrict__ ybuf)
{
    int e  = blockIdx.x >> 6;
    int mb = blockIdx.x & 63;
    int nb = blockIdx.y;
    int off = 0;
#pragma unroll
    for (int i = 0; i < NE; i++) { int c = clampi(counts[i], 0, NROWS); if (i < e) off += c; }
    int cnt  = clampi(counts[e], 0, NROWS);
    int row0 = mb * 64;
    if (row0 >= cnt) return;
    int nvalid = clampi(cnt - row0, 1, 64);

    __shared__ __align__(16) unsigned short lA[64 * 40];
    __shared__ __align__(16) unsigned short lB[64 * 40];
    __shared__ int   ltok2[64];
    __shared__ float lgate[64];

    int t = threadIdx.x;
    if (t < 64) {
        int rl = clampi(t, 0, nvalid - 1);
        int idx = clampi(off + row0 + rl, 0, NROWS - 1);
        ltok2[t] = clampi(row_tok[idx], 0, N_TOK - 1);
        lgate[t] = row_gate[idx];
    }
    __syncthreads();

    int wv = t >> 6, lane = t & 63, quad = lane >> 4, ln = lane & 15;
    f32x4 acc[4];
#pragma unroll
    for (int s = 0; s < 4; s++) acc[s] = (f32x4){0.f, 0.f, 0.f, 0.f};

    int ai = t >> 2, ac = t & 3;
    int bk = t >> 3, bc = t & 7;
    const int n0 = nb * 64;
    int arow_idx = clampi(off + row0 + clampi(ai, 0, nvalid - 1), 0, NROWS - 1);
    const unsigned short* Arow = h + (size_t)arow_idx * HID + ac * 8;
    const float* Bbase = w2 + (size_t)e * HID * DIM + n0;

    for (int kt = 0; kt < HID / 32; kt++) {
        int k0 = kt * 32;
        uint4 av = *(const uint4*)(Arow + k0);
        unsigned short b8[8];
        load8f(Bbase + (size_t)(k0 + bk) * DIM + bc * 8, b8);
        *(uint4*)(&lA[ai * 40 + ac * 8]) = av;
#pragma unroll
        for (int j = 0; j < 8; j++) lB[(bc * 8 + j) * 40 + bk] = b8[j];
        __syncthreads();
        bf16x8 afr = *(const bf16x8*)(&lA[(wv * 16 + ln) * 40 + quad * 8]);
#pragma unroll
        for (int s = 0; s < 4; s++) {
            bf16x8 bfr = *(const bf16x8*)(&lB[(s * 16 + ln) * 40 + quad * 8]);
            acc[s] = __builtin_amdgcn_mfma_f32_16x16x32_bf16(afr, bfr, acc[s], 0, 0, 0);
        }
        __syncthreads();
    }

#pragma unroll
    for (int s = 0; s < 4; s++) {
        int col = n0 + s * 16 + ln;
        float bias = b2[e * DIM + col];
#pragma unroll
        for (int r = 0; r < 4; r++) {
            int ml = wv * 16 + quad * 4 + r;
            if (ml < nvalid) {
                float vv = (acc[s][r] + bias) * lgate[ml];
                atomicAdd(&ybuf[(size_t)ltok2[ml] * DIM + col], vv);
            }
        }
    }
}

__global__ __launch_bounds__(256) void copy_kernel(
    const float4* __restrict__ ybuf4, float4* __restrict__ out4)
{
    int i = blockIdx.x * 256 + threadIdx.x;
    out4[i] = ybuf4[i];
}

__global__ __launch_bounds__(256) void zero_out_kernel(float* __restrict__ out) {
    int i = blockIdx.x * 256 + threadIdx.x;
    out[i] = 0.f;
}

// ================= host =================
extern "C" void kernel_launch(void* const* d_in, const int* in_sizes, int n_in,
                              void* d_out, int out_size, void* d_ws, size_t ws_size,
                              hipStream_t stream) {
    const float* x  = (const float*)d_in[0];
    const float* wg = (const float*)d_in[1];
    const float* w1 = (const float*)d_in[2];
    const float* b1 = (const float*)d_in[3];
    const float* w2 = (const float*)d_in[4];
    const float* b2 = (const float*)d_in[5];
    float* out = (float*)d_out;

    char* ws = (char*)d_ws;
    int*   counts   = (int*)(ws + 0);
    int*   cursors  = (int*)(ws + 64);
    int*   top_e    = (int*)(ws + 256);
    float* top_g    = (float*)(ws + 16640);
    int*   row_tok  = (int*)(ws + 49408);
    float* row_gate = (float*)(ws + 82176);

    // fast layout: [128K, +32M) wT (w1T then w2T, reused) ; [128K+32M, +32M) hbuf
    const size_t WT_OFF      = (size_t)1 << 17;
    const size_t HBUF_F_OFF  = WT_OFF + (size_t)NE * DIM * HID * 2;        // 32 MB
    const size_t NEEDED_FAST = HBUF_F_OFF + (size_t)NROWS * HID * 2;       // 64.125 MB

    // slow layout: [128K, +32M) hbuf ; then 16 MB ybuf
    const size_t HBUF_S_OFF  = (size_t)1 << 17;
    const size_t YBUF_OFF    = HBUF_S_OFF + (size_t)NROWS * HID * 2;
    const size_t NEEDED_SLOW = YBUF_OFF + (size_t)N_TOK * DIM * 4;         // 48.125 MB

    if (ws_size >= NEEDED_FAST) {
        unsigned short* wt   = (unsigned short*)(ws + WT_OFF);
        unsigned short* hbuf = (unsigned short*)(ws + HBUF_F_OFF);

        init_out_kernel<<<dim3(N_TOK * DIM / 1024), dim3(256), 0, stream>>>((int*)ws, (float4*)out);
        gate_kernel<<<dim3(N_TOK / 4), dim3(256), 0, stream>>>(x, wg, counts, top_e, top_g);
        scatter_kernel<<<dim3(N_TOK / 256), dim3(256), 0, stream>>>(counts, cursors, top_e, top_g, row_tok, row_gate);
        // w1 [e][D][H] -> w1T [e][H][D]
        transpose_kernel<<<dim3(DIM / 64, HID / 64, NE), dim3(256), 0, stream>>>(w1, wt, DIM, HID);
        ffn1_fast<<<dim3(NE * 64, HID / 128), dim3(256), 0, stream>>>(x, wt, b1, counts, row_tok, hbuf);
        // w2 [e][H][D] -> w2T [e][D][H]  (reuses wt region after ffn1 completes)
        transpose_kernel<<<dim3(HID / 64, DIM / 64, NE), dim3(256), 0, stream>>>(w2, wt, HID, DIM);
        ffn2_fast<<<dim3(NE * 64, DIM / 128), dim3(256), 0, stream>>>(hbuf, wt, b2, counts, row_tok, row_gate, out);
    } else if (ws_size >= NEEDED_SLOW) {
        unsigned short* hbuf = (unsigned short*)(ws + HBUF_S_OFF);
        float* ybuf = (float*)(ws + YBUF_OFF);
        init_kernel<<<dim3(N_TOK * DIM / 1024), dim3(256), 0, stream>>>((int*)ws, (float4*)ybuf);
        gate_kernel<<<dim3(N_TOK / 4), dim3(256), 0, stream>>>(x, wg, counts, top_e, top_g);
        scatter_kernel<<<dim3(N_TOK / 256), dim3(256), 0, stream>>>(counts, cursors, top_e, top_g, row_tok, row_gate);
        ffn1_kernel<<<dim3(NE * 64, HID / 64), dim3(256), 0, stream>>>(x, w1, b1, counts, row_tok, hbuf);
        ffn2_kernel<<<dim3(NE * 64, DIM / 64), dim3(256), 0, stream>>>(hbuf, w2, b2, counts, row_tok, row_gate, ybuf);
        copy_kernel<<<dim3(N_TOK * DIM / 1024), dim3(256), 0, stream>>>((const float4*)ybuf, (float4*)out);
    } else {
        zero_out_kernel<<<dim3(N_TOK * DIM / 256), dim3(256), 0, stream>>>(out);
    }
}

// Round 9
// 556.968 us; speedup vs baseline: 1.7353x; 1.6289x over previous
//
#include <hip/hip_runtime.h>
#include <math.h>
#include <stdint.h>

#define N_TOK 4096
#define DIM   1024
#define HID   2048
#define NE    8
#define NROWS (N_TOK * 2)   // 8192 (token, k) assignments
#define LDST  72            // LDS tile stride in shorts (36 dwords; balanced banks, 16B-aligned)
#define NB1   (HID / 128)   // 16 col-tiles in ffn1
#define NB2   (DIM / 128)   // 8 col-tiles in ffn2

typedef __attribute__((ext_vector_type(8))) short bf16x8;
typedef __attribute__((ext_vector_type(4))) float f32x4;

__device__ __forceinline__ unsigned short f2bf(float f) {
    union { unsigned int i; float f; } v; v.f = f;
    unsigned int u = v.i;
    return (unsigned short)((u + 0x7FFFu + ((u >> 16) & 1u)) >> 16);
}
__device__ __forceinline__ int clampi(int v, int lo, int hi) {
    return v < lo ? lo : (v > hi ? hi : v);
}
__device__ __forceinline__ void cvt8(const float* p, unsigned short* o) {
    float4 a = *(const float4*)p;
    float4 b = *(const float4*)(p + 4);
    o[0] = f2bf(a.x); o[1] = f2bf(a.y); o[2] = f2bf(a.z); o[3] = f2bf(a.w);
    o[4] = f2bf(b.x); o[5] = f2bf(b.y); o[6] = f2bf(b.z); o[7] = f2bf(b.w);
}

// ---------------- init (fast path): zero header + d_out ----------------
__global__ __launch_bounds__(256) void init_out_kernel(int* __restrict__ hdr, float4* __restrict__ out4) {
    int i = blockIdx.x * 256 + threadIdx.x;     // 4096 blocks -> 1M float4
    out4[i] = make_float4(0.f, 0.f, 0.f, 0.f);
    if (i < 32) hdr[i] = 0;
}

// ---------------- gating: one wave per token, pure fp32 ----------------
__global__ __launch_bounds__(256) void gate_kernel(
    const float* __restrict__ x, const float* __restrict__ wg,
    int* __restrict__ counts, int* __restrict__ top_e, float* __restrict__ top_g)
{
    int wave = threadIdx.x >> 6;
    int lane = threadIdx.x & 63;
    int n = blockIdx.x * 4 + wave;
    if (n >= N_TOK) return;
    float acc[NE];
#pragma unroll
    for (int e = 0; e < NE; e++) acc[e] = 0.f;
    const float* xrow = x + (size_t)n * DIM;
    for (int d = lane; d < DIM; d += 64) {
        float xv = xrow[d];
        float4 wa = *(const float4*)(wg + (size_t)d * NE);
        float4 wb = *(const float4*)(wg + (size_t)d * NE + 4);
        acc[0] += xv * wa.x; acc[1] += xv * wa.y;
        acc[2] += xv * wa.z; acc[3] += xv * wa.w;
        acc[4] += xv * wb.x; acc[5] += xv * wb.y;
        acc[6] += xv * wb.z; acc[7] += xv * wb.w;
    }
#pragma unroll
    for (int e = 0; e < NE; e++) {
        float v = acc[e];
#pragma unroll
        for (int off = 32; off > 0; off >>= 1) v += __shfl_xor(v, off, 64);
        acc[e] = v;
    }
    if (lane == 0) {
        int e0 = 0; float v0 = acc[0];
#pragma unroll
        for (int e = 1; e < NE; e++) if (acc[e] > v0) { v0 = acc[e]; e0 = e; }
        int e1 = (e0 == 0) ? 1 : 0; float v1 = acc[e1];
#pragma unroll
        for (int e = 0; e < NE; e++) if (e != e0 && acc[e] > v1) { v1 = acc[e]; e1 = e; }
        float s = expf(v1 - v0);
        float g0 = 1.f / (1.f + s);
        float g1 = s / (1.f + s);
        atomicAdd(&counts[e0], 1);
        atomicAdd(&counts[e1], 1);
        top_e[n] = e0 | (e1 << 8);
        top_g[2 * n + 0] = g0;
        top_g[2 * n + 1] = g1;
    }
}

// ---------------- scatter: build per-expert row lists ----------------
__global__ __launch_bounds__(256) void scatter_kernel(
    const int* __restrict__ counts, int* __restrict__ cursors,
    const int* __restrict__ top_e, const float* __restrict__ top_g,
    int* __restrict__ row_tok, float* __restrict__ row_gate)
{
    int n = blockIdx.x * 256 + threadIdx.x;
    if (n >= N_TOK) return;
    int off[NE]; int a = 0;
#pragma unroll
    for (int e = 0; e < NE; e++) { off[e] = a; a += clampi(counts[e], 0, NROWS); }
    int te = top_e[n];
#pragma unroll
    for (int k = 0; k < 2; k++) {
        int e = clampi((k == 0) ? (te & 0xFF) : ((te >> 8) & 0xFF), 0, NE - 1);
        int pos = atomicAdd(&cursors[e], 1);
        int r = clampi(off[e] + pos, 0, NROWS - 1);
        row_tok[r]  = n;
        row_gate[r] = top_g[2 * n + k];
    }
}

// ---------------- transpose+cast: in[e][K][N] fp32 -> out[e][N][K] bf16 ----------------
__global__ __launch_bounds__(256) void transpose_kernel(
    const float* __restrict__ in, unsigned short* __restrict__ outp, int K, int N)
{
    int e  = blockIdx.z;
    int kb = blockIdx.x;        // K/64 tiles
    int nb = blockIdx.y;        // N/64 tiles
    __shared__ __align__(16) unsigned short tile[64 * LDST];
    int t = threadIdx.x;

    int r = t >> 2, cq = t & 3;
    const float* sp = in + ((size_t)e * K + kb * 64 + r) * N + nb * 64 + cq * 16;
    unsigned short v[16];
    cvt8(sp, v);
    cvt8(sp + 8, v + 8);
    *(uint4*)(&tile[r * LDST + cq * 16 + 0]) = *(uint4*)(v + 0);
    *(uint4*)(&tile[r * LDST + cq * 16 + 8]) = *(uint4*)(v + 8);
    __syncthreads();

    int c = t >> 2, kq = t & 3;
    unsigned short o[16];
#pragma unroll
    for (int i = 0; i < 16; i++) o[i] = tile[(kq * 16 + i) * LDST + c];
    unsigned short* dp = outp + ((size_t)e * N + nb * 64 + c) * K + kb * 64 + kq * 16;
    *(uint4*)(dp + 0) = *(uint4*)(o + 0);
    *(uint4*)(dp + 8) = *(uint4*)(o + 8);
}

// ---------------- FFN1 fast: 128x128 tile, BK=64, w1T bf16 ----------------
// 1-D grid, mb-major decode: id = (mb*NE + e)*NB1 + nb  => working blocks (small mb)
// are contiguous ids -> spread across all XCDs/CUs (fixes the 32-CU clustering of r8).
__global__ __launch_bounds__(256) void ffn1_fast(
    const float* __restrict__ x,
    const unsigned short* __restrict__ w1t,   // [e][H][D] bf16
    const float* __restrict__ b1,
    const int* __restrict__ counts,
    const int* __restrict__ row_tok,
    unsigned short* __restrict__ h)
{
    int id = blockIdx.x;
    int nb = id % NB1;
    int rest = id / NB1;
    int e  = rest % NE;
    int mb = rest / NE;

    int off = 0;
#pragma unroll
    for (int i = 0; i < NE; i++) { int c = clampi(counts[i], 0, NROWS); if (i < e) off += c; }
    int cnt  = clampi(counts[e], 0, NROWS);
    int row0 = mb * 128;
    if (row0 >= cnt) return;
    int nvalid = clampi(cnt - row0, 1, 128);

    __shared__ __align__(16) unsigned short lA[128 * LDST];  // 18 KB
    __shared__ __align__(16) unsigned short lB[128 * LDST];  // 18 KB
    __shared__ int ltok[128];

    int t = threadIdx.x;
    if (t < 128) {
        int rl = clampi(t, 0, nvalid - 1);
        int idx = clampi(off + row0 + rl, 0, NROWS - 1);
        ltok[t] = clampi(row_tok[idx], 0, N_TOK - 1);
    }
    __syncthreads();

    const int n0 = nb * 128;
    const float* aptr[4];
    const unsigned short* bptr[4];
    int lofs[4];
#pragma unroll
    for (int i = 0; i < 4; i++) {
        int id2 = i * 256 + t;
        int row = id2 >> 3, kc = id2 & 7;
        aptr[i] = x + (size_t)ltok[row] * DIM + kc * 8;
        bptr[i] = w1t + ((size_t)e * HID + n0 + row) * DIM + kc * 8;
        lofs[i] = row * LDST + kc * 8;
    }

    int wv = t >> 6, lane = t & 63, quad = lane >> 4, ln = lane & 15;
    int wr = wv >> 1, wc = wv & 1;
    f32x4 acc[4][4];
#pragma unroll
    for (int i = 0; i < 4; i++)
#pragma unroll
        for (int j = 0; j < 4; j++) acc[i][j] = (f32x4){0.f, 0.f, 0.f, 0.f};

    for (int kt = 0; kt < DIM / 64; kt++) {
        int k0 = kt * 64;
#pragma unroll
        for (int i = 0; i < 4; i++) {
            unsigned short a8[8];
            cvt8(aptr[i] + k0, a8);
            *(uint4*)(&lA[lofs[i]]) = *(uint4*)a8;
            *(uint4*)(&lB[lofs[i]]) = *(const uint4*)(bptr[i] + k0);
        }
        __syncthreads();
#pragma unroll
        for (int kk = 0; kk < 2; kk++) {
            bf16x8 af[4], bf[4];
#pragma unroll
            for (int s = 0; s < 4; s++)
                af[s] = *(const bf16x8*)(&lA[(wr * 64 + s * 16 + ln) * LDST + kk * 32 + quad * 8]);
#pragma unroll
            for (int s = 0; s < 4; s++)
                bf[s] = *(const bf16x8*)(&lB[(wc * 64 + s * 16 + ln) * LDST + kk * 32 + quad * 8]);
#pragma unroll
            for (int i = 0; i < 4; i++)
#pragma unroll
                for (int j = 0; j < 4; j++)
                    acc[i][j] = __builtin_amdgcn_mfma_f32_16x16x32_bf16(af[i], bf[j], acc[i][j], 0, 0, 0);
        }
        __syncthreads();
    }

    int gr0 = off + row0;
#pragma unroll
    for (int j = 0; j < 4; j++) {
        int col = n0 + wc * 64 + j * 16 + ln;
        float bias = b1[e * HID + col];
#pragma unroll
        for (int i = 0; i < 4; i++) {
#pragma unroll
            for (int r = 0; r < 4; r++) {
                int m = wr * 64 + i * 16 + quad * 4 + r;
                if (m < nvalid) {
                    float vv = acc[i][j][r] + bias;
                    float c = 0.7978845608028654f * (vv + 0.044715f * vv * vv * vv);
                    float g = 0.5f * vv * (1.f + tanhf(c));
                    h[(size_t)(gr0 + m) * HID + col] = f2bf(g);
                }
            }
        }
    }
}

// ---------------- FFN2 fast: 128x128 tile, BK=64, w2T bf16, atomic into out ----------------
__global__ __launch_bounds__(256) void ffn2_fast(
    const unsigned short* __restrict__ h,
    const unsigned short* __restrict__ w2t,   // [e][D][H] bf16
    const float* __restrict__ b2,
    const int* __restrict__ counts,
    const int* __restrict__ row_tok,
    const float* __restrict__ row_gate,
    float* __restrict__ out)
{
    int id = blockIdx.x;
    int nb = id % NB2;
    int rest = id / NB2;
    int e  = rest % NE;
    int mb = rest / NE;

    int off = 0;
#pragma unroll
    for (int i = 0; i < NE; i++) { int c = clampi(counts[i], 0, NROWS); if (i < e) off += c; }
    int cnt  = clampi(counts[e], 0, NROWS);
    int row0 = mb * 128;
    if (row0 >= cnt) return;
    int nvalid = clampi(cnt - row0, 1, 128);

    __shared__ __align__(16) unsigned short lA[128 * LDST];
    __shared__ __align__(16) unsigned short lB[128 * LDST];
    __shared__ int   ltok2[128];
    __shared__ float lgate[128];

    int t = threadIdx.x;
    if (t < 128) {
        int rl = clampi(t, 0, nvalid - 1);
        int idx = clampi(off + row0 + rl, 0, NROWS - 1);
        ltok2[t] = clampi(row_tok[idx], 0, N_TOK - 1);
        lgate[t] = row_gate[idx];
    }
    __syncthreads();

    const int n0 = nb * 128;
    const unsigned short* aptr[4];
    const unsigned short* bptr[4];
    int lofs[4];
#pragma unroll
    for (int i = 0; i < 4; i++) {
        int id2 = i * 256 + t;
        int row = id2 >> 3, kc = id2 & 7;
        int arow = clampi(off + row0 + clampi(row, 0, nvalid - 1), 0, NROWS - 1);
        aptr[i] = h + (size_t)arow * HID + kc * 8;
        bptr[i] = w2t + ((size_t)e * DIM + n0 + row) * HID + kc * 8;
        lofs[i] = row * LDST + kc * 8;
    }

    int wv = t >> 6, lane = t & 63, quad = lane >> 4, ln = lane & 15;
    int wr = wv >> 1, wc = wv & 1;
    f32x4 acc[4][4];
#pragma unroll
    for (int i = 0; i < 4; i++)
#pragma unroll
        for (int j = 0; j < 4; j++) acc[i][j] = (f32x4){0.f, 0.f, 0.f, 0.f};

    for (int kt = 0; kt < HID / 64; kt++) {
        int k0 = kt * 64;
#pragma unroll
        for (int i = 0; i < 4; i++) {
            *(uint4*)(&lA[lofs[i]]) = *(const uint4*)(aptr[i] + k0);
            *(uint4*)(&lB[lofs[i]]) = *(const uint4*)(bptr[i] + k0);
        }
        __syncthreads();
#pragma unroll
        for (int kk = 0; kk < 2; kk++) {
            bf16x8 af[4], bf[4];
#pragma unroll
            for (int s = 0; s < 4; s++)
                af[s] = *(const bf16x8*)(&lA[(wr * 64 + s * 16 + ln) * LDST + kk * 32 + quad * 8]);
#pragma unroll
            for (int s = 0; s < 4; s++)
                bf[s] = *(const bf16x8*)(&lB[(wc * 64 + s * 16 + ln) * LDST + kk * 32 + quad * 8]);
#pragma unroll
            for (int i = 0; i < 4; i++)
#pragma unroll
                for (int j = 0; j < 4; j++)
                    acc[i][j] = __builtin_amdgcn_mfma_f32_16x16x32_bf16(af[i], bf[j], acc[i][j], 0, 0, 0);
        }
        __syncthreads();
    }

#pragma unroll
    for (int j = 0; j < 4; j++) {
        int col = n0 + wc * 64 + j * 16 + ln;
        float bias = b2[e * DIM + col];
#pragma unroll
        for (int i = 0; i < 4; i++) {
#pragma unroll
            for (int r = 0; r < 4; r++) {
                int m = wr * 64 + i * 16 + quad * 4 + r;
                if (m < nvalid) {
                    float vv = (acc[i][j][r] + bias) * lgate[m];
                    atomicAdd(&out[(size_t)ltok2[m] * DIM + col], vv);
                }
            }
        }
    }
}

// ================= slow fallback path (round-7, known-good) =================
__device__ __forceinline__ void load8f(const float* p, unsigned short* o) { cvt8(p, o); }

__global__ __launch_bounds__(256) void init_kernel(int* __restrict__ hdr, float4* __restrict__ ybuf4) {
    int i = blockIdx.x * 256 + threadIdx.x;
    ybuf4[i] = make_float4(0.f, 0.f, 0.f, 0.f);
    if (i < 32) hdr[i] = 0;
}

__global__ __launch_bounds__(256) void ffn1_kernel(
    const float* __restrict__ x, const float* __restrict__ w1, const float* __restrict__ b1,
    const int* __restrict__ counts, const int* __restrict__ row_tok, unsigned short* __restrict__ h)
{
    int e  = blockIdx.x >> 6;
    int mb = blockIdx.x & 63;
    int nb = blockIdx.y;
    int off = 0;
#pragma unroll
    for (int i = 0; i < NE; i++) { int c = clampi(counts[i], 0, NROWS); if (i < e) off += c; }
    int cnt  = clampi(counts[e], 0, NROWS);
    int row0 = mb * 64;
    if (row0 >= cnt) return;
    int nvalid = clampi(cnt - row0, 1, 64);

    __shared__ __align__(16) unsigned short lA[64 * 40];
    __shared__ __align__(16) unsigned short lB[64 * 40];
    __shared__ int ltok[64];

    int t = threadIdx.x;
    if (t < 64) {
        int rl = clampi(t, 0, nvalid - 1);
        int idx = clampi(off + row0 + rl, 0, NROWS - 1);
        ltok[t] = clampi(row_tok[idx], 0, N_TOK - 1);
    }
    __syncthreads();

    int wv = t >> 6, lane = t & 63, quad = lane >> 4, ln = lane & 15;
    f32x4 acc[4];
#pragma unroll
    for (int s = 0; s < 4; s++) acc[s] = (f32x4){0.f, 0.f, 0.f, 0.f};

    int ai = t >> 2, ac = t & 3;
    int bk = t >> 3, bc = t & 7;
    const int n0 = nb * 64;
    const float* Arow  = x + (size_t)ltok[ai] * DIM + ac * 8;
    const float* Bbase = w1 + (size_t)e * DIM * HID + n0;

    for (int kt = 0; kt < DIM / 32; kt++) {
        int k0 = kt * 32;
        unsigned short a8[8], b8[8];
        load8f(Arow + k0, a8);
        load8f(Bbase + (size_t)(k0 + bk) * HID + bc * 8, b8);
        *(uint4*)(&lA[ai * 40 + ac * 8]) = *(uint4*)a8;
#pragma unroll
        for (int j = 0; j < 8; j++) lB[(bc * 8 + j) * 40 + bk] = b8[j];
        __syncthreads();
        bf16x8 afr = *(const bf16x8*)(&lA[(wv * 16 + ln) * 40 + quad * 8]);
#pragma unroll
        for (int s = 0; s < 4; s++) {
            bf16x8 bfr = *(const bf16x8*)(&lB[(s * 16 + ln) * 40 + quad * 8]);
            acc[s] = __builtin_amdgcn_mfma_f32_16x16x32_bf16(afr, bfr, acc[s], 0, 0, 0);
        }
        __syncthreads();
    }

    int gr0 = off + row0;
#pragma unroll
    for (int s = 0; s < 4; s++) {
        int col = n0 + s * 16 + ln;
        float bias = b1[e * HID + col];
#pragma unroll
        for (int r = 0; r < 4; r++) {
            int ml = wv * 16 + quad * 4 + r;
            if (ml < nvalid) {
                float vv = acc[s][r] + bias;
                float c = 0.7978845608028654f * (vv + 0.044715f * vv * vv * vv);
                float g = 0.5f * vv * (1.f + tanhf(c));
                int hr = clampi(gr0 + ml, 0, NROWS - 1);
                h[(size_t)hr * HID + col] = f2bf(g);
            }
        }
    }
}

__global__ __launch_bounds__(256) void ffn2_kernel(
    const unsigned short* __restrict__ h, const float* __restrict__ w2, const float* __restrict__ b2,
    const int* __restrict__ counts, const int* __restrict__ row_tok, const float* __restrict__ row_gate,
    float* __restrict__ ybuf)
{
    int e  = blockIdx.x >> 6;
    int mb = blockIdx.x & 63;
    int nb = blockIdx.y;
    int off = 0;
#pragma unroll
    for (int i = 0; i < NE; i++) { int c = clampi(counts[i], 0, NROWS); if (i < e) off += c; }
    int cnt  = clampi(counts[e], 0, NROWS);
    int row0 = mb * 64;
    if (row0 >= cnt) return;
    int nvalid = clampi(cnt - row0, 1, 64);

    __shared__ __align__(16) unsigned short lA[64 * 40];
    __shared__ __align__(16) unsigned short lB[64 * 40];
    __shared__ int   ltok2[64];
    __shared__ float lgate[64];

    int t = threadIdx.x;
    if (t < 64) {
        int rl = clampi(t, 0, nvalid - 1);
        int idx = clampi(off + row0 + rl, 0, NROWS - 1);
        ltok2[t] = clampi(row_tok[idx], 0, N_TOK - 1);
        lgate[t] = row_gate[idx];
    }
    __syncthreads();

    int wv = t >> 6, lane = t & 63, quad = lane >> 4, ln = lane & 15;
    f32x4 acc[4];
#pragma unroll
    for (int s = 0; s < 4; s++) acc[s] = (f32x4){0.f, 0.f, 0.f, 0.f};

    int ai = t >> 2, ac = t & 3;
    int bk = t >> 3, bc = t & 7;
    const int n0 = nb * 64;
    int arow_idx = clampi(off + row0 + clampi(ai, 0, nvalid - 1), 0, NROWS - 1);
    const unsigned short* Arow = h + (size_t)arow_idx * HID + ac * 8;
    const float* Bbase = w2 + (size_t)e * HID * DIM + n0;

    for (int kt = 0; kt < HID / 32; kt++) {
        int k0 = kt * 32;
        uint4 av = *(const uint4*)(Arow + k0);
        unsigned short b8[8];
        load8f(Bbase + (size_t)(k0 + bk) * DIM + bc * 8, b8);
        *(uint4*)(&lA[ai * 40 + ac * 8]) = av;
#pragma unroll
        for (int j = 0; j < 8; j++) lB[(bc * 8 + j) * 40 + bk] = b8[j];
        __syncthreads();
        bf16x8 afr = *(const bf16x8*)(&lA[(wv * 16 + ln) * 40 + quad * 8]);
#pragma unroll
        for (int s = 0; s < 4; s++) {
            bf16x8 bfr = *(const bf16x8*)(&lB[(s * 16 + ln) * 40 + quad * 8]);
            acc[s] = __builtin_amdgcn_mfma_f32_16x16x32_bf16(afr, bfr, acc[s], 0, 0, 0);
        }
        __syncthreads();
    }

#pragma unroll
    for (int s = 0; s < 4; s++) {
        int col = n0 + s * 16 + ln;
        float bias = b2[e * DIM + col];
#pragma unroll
        for (int r = 0; r < 4; r++) {
            int ml = wv * 16 + quad * 4 + r;
            if (ml < nvalid) {
                float vv = (acc[s][r] + bias) * lgate[ml];
                atomicAdd(&ybuf[(size_t)ltok2[ml] * DIM + col], vv);
            }
        }
    }
}

__global__ __launch_bounds__(256) void copy_kernel(
    const float4* __restrict__ ybuf4, float4* __restrict__ out4)
{
    int i = blockIdx.x * 256 + threadIdx.x;
    out4[i] = ybuf4[i];
}

__global__ __launch_bounds__(256) void zero_out_kernel(float* __restrict__ out) {
    int i = blockIdx.x * 256 + threadIdx.x;
    out[i] = 0.f;
}

// ================= host =================
extern "C" void kernel_launch(void* const* d_in, const int* in_sizes, int n_in,
                              void* d_out, int out_size, void* d_ws, size_t ws_size,
                              hipStream_t stream) {
    const float* x  = (const float*)d_in[0];
    const float* wg = (const float*)d_in[1];
    const float* w1 = (const float*)d_in[2];
    const float* b1 = (const float*)d_in[3];
    const float* w2 = (const float*)d_in[4];
    const float* b2 = (const float*)d_in[5];
    float* out = (float*)d_out;

    char* ws = (char*)d_ws;
    int*   counts   = (int*)(ws + 0);
    int*   cursors  = (int*)(ws + 64);
    int*   top_e    = (int*)(ws + 256);
    float* top_g    = (float*)(ws + 16640);
    int*   row_tok  = (int*)(ws + 49408);
    float* row_gate = (float*)(ws + 82176);

    const size_t WT_OFF      = (size_t)1 << 17;
    const size_t HBUF_F_OFF  = WT_OFF + (size_t)NE * DIM * HID * 2;        // 32 MB
    const size_t NEEDED_FAST = HBUF_F_OFF + (size_t)NROWS * HID * 2;       // 64.125 MB

    const size_t HBUF_S_OFF  = (size_t)1 << 17;
    const size_t YBUF_OFF    = HBUF_S_OFF + (size_t)NROWS * HID * 2;
    const size_t NEEDED_SLOW = YBUF_OFF + (size_t)N_TOK * DIM * 4;         // 48.125 MB

    if (ws_size >= NEEDED_FAST) {
        unsigned short* wt   = (unsigned short*)(ws + WT_OFF);
        unsigned short* hbuf = (unsigned short*)(ws + HBUF_F_OFF);

        init_out_kernel<<<dim3(N_TOK * DIM / 1024), dim3(256), 0, stream>>>((int*)ws, (float4*)out);
        gate_kernel<<<dim3(N_TOK / 4), dim3(256), 0, stream>>>(x, wg, counts, top_e, top_g);
        scatter_kernel<<<dim3(N_TOK / 256), dim3(256), 0, stream>>>(counts, cursors, top_e, top_g, row_tok, row_gate);
        // w1 [e][D][H] -> w1T [e][H][D]
        transpose_kernel<<<dim3(DIM / 64, HID / 64, NE), dim3(256), 0, stream>>>(w1, wt, DIM, HID);
        ffn1_fast<<<dim3(64 * NE * NB1), dim3(256), 0, stream>>>(x, wt, b1, counts, row_tok, hbuf);
        // w2 [e][H][D] -> w2T [e][D][H]
        transpose_kernel<<<dim3(HID / 64, DIM / 64, NE), dim3(256), 0, stream>>>(w2, wt, HID, DIM);
        ffn2_fast<<<dim3(64 * NE * NB2), dim3(256), 0, stream>>>(hbuf, wt, b2, counts, row_tok, row_gate, out);
    } else if (ws_size >= NEEDED_SLOW) {
        unsigned short* hbuf = (unsigned short*)(ws + HBUF_S_OFF);
        float* ybuf = (float*)(ws + YBUF_OFF);
        init_kernel<<<dim3(N_TOK * DIM / 1024), dim3(256), 0, stream>>>((int*)ws, (float4*)ybuf);
        gate_kernel<<<dim3(N_TOK / 4), dim3(256), 0, stream>>>(x, wg, counts, top_e, top_g);
        scatter_kernel<<<dim3(N_TOK / 256), dim3(256), 0, stream>>>(counts, cursors, top_e, top_g, row_tok, row_gate);
        ffn1_kernel<<<dim3(NE * 64, HID / 64), dim3(256), 0, stream>>>(x, w1, b1, counts, row_tok, hbuf);
        ffn2_kernel<<<dim3(NE * 64, DIM / 64), dim3(256), 0, stream>>>(hbuf, w2, b2, counts, row_tok, row_gate, ybuf);
        copy_kernel<<<dim3(N_TOK * DIM / 1024), dim3(256), 0, stream>>>((const float4*)ybuf, (float4*)out);
    } else {
        zero_out_kernel<<<dim3(N_TOK * DIM / 256), dim3(256), 0, stream>>>(out);
    }
}